// Round 15
// baseline (771.284 us; speedup 1.0000x reference)
//
#include <hip/hip_runtime.h>
#include <hip/hip_bf16.h>

// GraphConvNet on MI355X — round 15: ws-adaptive eh0 materialization.
// r14 = 760us (edge 2x283 = 74%). All edge scheduling levers falsified; only
// instruction removal works (gelu 1:1, atomics). Biggest removable block:
// STEP1's embed recompute (40 MFMA + ~170 VALU/LDS + 2 LDS waits/wave), kept
// only because eh0 (128MB) broke the proven 180MB ws envelope. Actual ws_size
// unknown -> probe at runtime: allocate eh0g only if it fits (host-side,
// deterministic, capture-safe); else exact r14 fallback.
//   STEP0 (+EHIO): store a1[c] fragments to eh0g (4x16B vector stores/lane).
//   STEP1 (+EHIO): skip embed entirely; load a1[c] from eh0g.
//
// MFMA fragment facts (guide §3, m89/m91/m120 verified):
//   A: lane holds A[m=lane&15][k=(lane>>4)*8+j]
//   B: lane holds B[k=(lane>>4)*8+j][n=lane&15]
//   C/D: lane reg r holds C[row=(lane>>4)*4+r][col=lane&15]

typedef __bf16 bf16;
typedef __attribute__((ext_vector_type(8))) __bf16 bf16x8;
typedef __attribute__((ext_vector_type(2))) __bf16 bf16x2;
typedef __attribute__((ext_vector_type(4))) float f32x4;

__device__ __forceinline__ float gelu_t(float x) {
    // exact identity: 0.5x(1+tanh(u)) == x*sigmoid(2u) = x/(1+exp(-2u))
    const float kn0 = -1.5957691216057308f;   // -2*sqrt(2/pi)
    const float kn1 = -0.07135481627159855f;  // -2*sqrt(2/pi)*0.044715
    float x2 = x * x;
    float w = x * __builtin_fmaf(kn1, x2, kn0);
    float e = __expf(w);
    return __fdividef(x, 1.0f + e);
}

// ---------------- weight packing: [K,128] fp32 -> bf16 [K/8][128][8] ----------------
struct PackDesc { const float* src; int Kcopy; int dstOff; };
struct PackArgs { PackDesc d[13]; };

__global__ __launch_bounds__(256) void pack_all_kernel(PackArgs pa, bf16* dst, int total) {
    int i = blockIdx.x * 256 + threadIdx.x;
    if (i >= total) return;
    int s = 0;
#pragma unroll
    for (int j = 1; j < 13; ++j) if (i >= pa.d[j].dstOff) s = j;
    int local = i - pa.d[s].dstOff;
    int k = local >> 7, n = local & 127;
    float v = (k < pa.d[s].Kcopy) ? pa.d[s].src[(size_t)k * 128 + n] : 0.0f;
    dst[pa.d[s].dstOff + ((k >> 3) * 128 + n) * 8 + (k & 7)] = (bf16)v;
}

__global__ void fold_bias_kernel(const float* g, const float* euW0, const float* eub0,
                                 const float* nuW0, const float* nub0,
                                 float* eu_eff, float* nu_eff) {
    int t = threadIdx.x;
    if (t < 128) {
        float g0 = g[0], g1 = g[1];
#pragma unroll
        for (int s = 0; s < 2; ++s) {
            eu_eff[s * 128 + t] = eub0[s * 128 + t]
                + g0 * euW0[((size_t)s * 386 + 384) * 128 + t]
                + g1 * euW0[((size_t)s * 386 + 385) * 128 + t];
            nu_eff[s * 128 + t] = nub0[s * 128 + t]
                + g0 * nuW0[((size_t)s * 258 + 256) * 128 + t]
                + g1 * nuW0[((size_t)s * 258 + 257) * 128 + t];
        }
    }
}

__global__ __launch_bounds__(256) void zero_kernel(float4* p, int n4) {
    int i = blockIdx.x * 256 + threadIdx.x;
    if (i < n4) p[i] = float4{0.0f, 0.0f, 0.0f, 0.0f};
}

// ---------------- receiver-sort (counting sort) ----------------
__global__ __launch_bounds__(256) void hist_kernel(const int* __restrict__ recv,
                                                   int* __restrict__ deg, int E) {
    int e = blockIdx.x * 256 + threadIdx.x;
    if (e < E) atomicAdd(&deg[recv[e]], 1);
}

__global__ __launch_bounds__(256) void scan_part_kernel(const int* __restrict__ deg,
                                                        int* __restrict__ cursor,
                                                        int* __restrict__ bsum, int n) {
    __shared__ int tmp[256];
    int t = threadIdx.x, g = blockIdx.x * 256 + t;
    int v = (g < n) ? deg[g] : 0;
    tmp[t] = v; __syncthreads();
#pragma unroll
    for (int o = 1; o < 256; o <<= 1) {
        int x = (t >= o) ? tmp[t - o] : 0;
        __syncthreads();
        tmp[t] += x;
        __syncthreads();
    }
    if (g < n) cursor[g] = tmp[t] - v;
    if (t == 255) bsum[blockIdx.x] = tmp[255];
}

__global__ void scan_top_kernel(int* bsum, int nb) {  // single block, nb<=256
    __shared__ int tmp[256];
    int t = threadIdx.x;
    int v = (t < nb) ? bsum[t] : 0;
    tmp[t] = v; __syncthreads();
#pragma unroll
    for (int o = 1; o < 256; o <<= 1) {
        int x = (t >= o) ? tmp[t - o] : 0;
        __syncthreads();
        tmp[t] += x;
        __syncthreads();
    }
    if (t < nb) bsum[t] = tmp[t] - v;
}

__global__ __launch_bounds__(256) void scan_add_kernel(int* __restrict__ cursor,
                                                       const int* __restrict__ bsum, int n) {
    int g = blockIdx.x * 256 + threadIdx.x;
    if (g < n) cursor[g] += bsum[blockIdx.x];
}

// scatter: also pre-sorts raw edge features (edges_s[pos] = edges[e])
__global__ __launch_bounds__(256) void scatter_kernel(
    const int* __restrict__ send, const int* __restrict__ recv,
    const float* __restrict__ edges_raw, int* __restrict__ cursor,
    float* __restrict__ edges_s, int* __restrict__ sendp, int* __restrict__ recvp, int E) {
    int e = blockIdx.x * 256 + threadIdx.x;
    if (e >= E) return;
    int r = recv[e];
    int pos = atomicAdd(&cursor[r], 1);
    sendp[pos] = send[e]; recvp[pos] = r;
    edges_s[(size_t)pos * 3]     = edges_raw[(size_t)e * 3];
    edges_s[(size_t)pos * 3 + 1] = edges_raw[(size_t)e * 3 + 1];
    edges_s[(size_t)pos * 3 + 2] = edges_raw[(size_t)e * 3 + 2];
}
// after scatter: cursor[i] == end offset of node i's segment (CSR row end)

// ---------------- segment-sum (4x-wide): recvb[i] = sum of newe rows ----------------
__global__ __launch_bounds__(256) void segsum_kernel(const bf16* __restrict__ newe,
                                                     const int* __restrict__ endoff,
                                                     bf16* __restrict__ recvb, int N) {
    int node = blockIdx.x * 4 + (threadIdx.x >> 6);
    if (node >= N) return;
    int lane = threadIdx.x & 63;
    int g = lane >> 4, cl = lane & 15;
    int start = (node == 0) ? 0 : endoff[node - 1];
    int end = endoff[node];
    float s[8] = {0, 0, 0, 0, 0, 0, 0, 0};
    for (int e = start + g; e < end; e += 4) {
        bf16x8 v = *(const bf16x8*)(newe + (size_t)e * 128 + cl * 8);
#pragma unroll
        for (int j = 0; j < 8; ++j) s[j] += (float)v[j];
    }
#pragma unroll
    for (int j = 0; j < 8; ++j) {
        s[j] += __shfl_xor(s[j], 16);
        s[j] += __shfl_xor(s[j], 32);
    }
    if (g == 0) {
        bf16x8 o;
#pragma unroll
        for (int j = 0; j < 8; ++j) o[j] = (bf16)s[j];
        *(bf16x8*)(recvb + (size_t)node * 128 + cl * 8) = o;
    }
}

// ---------------- edge megakernel ----------------
// STEP 0: eh0=embed(raw); [EHIO: store a1 frags -> eh0g]; newe <- MLP_s0(...)
// STEP 1: [EHIO: load a1 frags from eh0g | else recompute embed];
//         eh1 = LN(eh0+newe1); newe <- MLP_s1(...) (in-place)
template <int STEP, int EHIO>
__global__ __launch_bounds__(256, 5) void edge_kernel(
    const float* __restrict__ edges_s,
    const int* __restrict__ sendp, const int* __restrict__ recvp,
    const bf16* __restrict__ nh_b, bf16* __restrict__ newe,
    bf16* __restrict__ eh0g,
    const bf16* __restrict__ We0, const float* __restrict__ be0,
    const bf16* __restrict__ We1, const float* __restrict__ be1,
    const float* __restrict__ ln_s, const float* __restrict__ ln_b,
    const bf16* __restrict__ Ws0, const float* __restrict__ bs0,
    const bf16* __restrict__ Ws1, const float* __restrict__ bs1,
    int E)
{
    __shared__ __align__(16) bf16 Hsep[4 * 16 * 136];
    const int tid = threadIdx.x, lane = tid & 63, w = tid >> 6;
    const int n16 = lane & 15, quad = lane >> 4;
    const int m0 = blockIdx.x * 64;
    const int mrow = m0 + w * 16 + n16;
    int m = mrow; if (m >= E) m = E - 1;
    const int sIdx = sendp[m], rIdx = recvp[m];

    bf16* Hw = &Hsep[w * 16 * 136];
    const f32x4 z = {0.0f, 0.0f, 0.0f, 0.0f};
    f32x4 acc[8];
    bf16x8 a1[4];

    if constexpr (!(STEP == 1 && EHIO == 1)) {
        // ---- embed GEMM1 (K=32; quad0 carries the 3 raw feats, sorted) ----
#pragma unroll
        for (int t = 0; t < 8; ++t) acc[t] = z;
        {
            bf16x8 a;
#pragma unroll
            for (int j = 0; j < 8; ++j) a[j] = (bf16)0.0f;
            if (quad == 0) {
                a[0] = (bf16)edges_s[(size_t)m * 3];
                a[1] = (bf16)edges_s[(size_t)m * 3 + 1];
                a[2] = (bf16)edges_s[(size_t)m * 3 + 2];
            }
            const bf16* bp = We0 + ((size_t)(quad * 128 + n16)) * 8;
#pragma unroll
            for (int t = 0; t < 8; ++t) {
                bf16x8 b = *(const bf16x8*)(bp + t * 128);
                acc[t] = __builtin_amdgcn_mfma_f32_16x16x32_bf16(a, b, acc[t], 0, 0, 0);
            }
        }
        // gelu + be0 -> Hw (A-layout)
#pragma unroll
        for (int t = 0; t < 8; ++t) {
            float bb = be0[t * 16 + n16];
#pragma unroll
            for (int r = 0; r < 4; ++r)
                Hw[(quad * 4 + r) * 136 + t * 16 + n16] = (bf16)gelu_t(acc[t][r] + bb);
        }
        // ---- embed GEMM2 (K=128) -> eh0 (C-layout) ----
#pragma unroll
        for (int t = 0; t < 8; ++t) acc[t] = z;
#pragma unroll
        for (int kc = 0; kc < 128; kc += 32) {
            bf16x8 a = *(const bf16x8*)&Hw[n16 * 136 + kc + quad * 8];
            const bf16* bp = We1 + ((size_t)(((kc >> 3) + quad) * 128 + n16)) * 8;
#pragma unroll
            for (int t = 0; t < 8; ++t) {
                bf16x8 b = *(const bf16x8*)(bp + t * 128);
                acc[t] = __builtin_amdgcn_mfma_f32_16x16x32_bf16(a, b, acc[t], 0, 0, 0);
            }
        }
        // eh0 -> Hw (A-layout, bf16)
#pragma unroll
        for (int t = 0; t < 8; ++t) {
            float bb = be1[t * 16 + n16];
#pragma unroll
            for (int r = 0; r < 4; ++r)
                Hw[(quad * 4 + r) * 136 + t * 16 + n16] = (bf16)(acc[t][r] + bb);
        }
#pragma unroll
        for (int c = 0; c < 4; ++c)
            a1[c] = *(const bf16x8*)&Hw[n16 * 136 + c * 32 + quad * 8];

        if constexpr (STEP == 0 && EHIO == 1) {
            // persist eh0 fragments for STEP1 (bit-identical reuse)
            if (mrow < E) {
#pragma unroll
                for (int c = 0; c < 4; ++c)
                    *(bf16x8*)(eh0g + (size_t)mrow * 128 + c * 32 + quad * 8) = a1[c];
            }
        }
    } else {
        // STEP1 big-ws: load persisted eh0 fragments, skip embed entirely
#pragma unroll
        for (int c = 0; c < 4; ++c)
            a1[c] = *(const bf16x8*)(eh0g + (size_t)m * 128 + c * 32 + quad * 8);
    }

    if constexpr (STEP == 1) {
        // eh1 = LN(eh0 + newe1) on A-fragments; full row in lanes {n16,+16,+32,+48}
        float x[4][8];
        float sm = 0.0f, sq = 0.0f;
#pragma unroll
        for (int c = 0; c < 4; ++c) {
            bf16x8 ne = *(const bf16x8*)(newe + (size_t)m * 128 + c * 32 + quad * 8);
#pragma unroll
            for (int j = 0; j < 8; ++j) {
                float v = (float)a1[c][j] + (float)ne[j];
                x[c][j] = v; sm += v; sq += v * v;
            }
        }
        sm += __shfl_xor(sm, 16); sq += __shfl_xor(sq, 16);
        sm += __shfl_xor(sm, 32); sq += __shfl_xor(sq, 32);
        float mean = sm * (1.0f / 128.0f);
        float inv = rsqrtf(sq * (1.0f / 128.0f) - mean * mean + 1e-6f);
#pragma unroll
        for (int c = 0; c < 4; ++c)
#pragma unroll
            for (int j = 0; j < 8; ++j) {
                int col = c * 32 + quad * 8 + j;
                a1[c][j] = (bf16)((x[c][j] - mean) * inv * ln_s[col] + ln_b[col]);
            }
    }

    // ---- step GEMM1: K=384 = [eh | nh[send] | nh[recv]] ----
#pragma unroll
    for (int t = 0; t < 8; ++t) acc[t] = z;
#pragma unroll
    for (int c = 0; c < 12; ++c) {
        const int k0 = (c & 3) * 32 + quad * 8;
        bf16x8 af;
        if (c < 4)      af = a1[c];
        else if (c < 8) af = *(const bf16x8*)(nh_b + (size_t)sIdx * 128 + k0);
        else            af = *(const bf16x8*)(nh_b + (size_t)rIdx * 128 + k0);
        const bf16* bp = Ws0 + ((size_t)((c * 4 + quad) * 128 + n16)) * 8;
#pragma unroll
        for (int t = 0; t < 8; ++t) {
            bf16x8 b = *(const bf16x8*)(bp + t * 128);
            acc[t] = __builtin_amdgcn_mfma_f32_16x16x32_bf16(af, b, acc[t], 0, 0, 0);
        }
    }
    // gelu + bs0 -> Hw
#pragma unroll
    for (int t = 0; t < 8; ++t) {
        float bb = bs0[t * 16 + n16];
#pragma unroll
        for (int r = 0; r < 4; ++r)
            Hw[(quad * 4 + r) * 136 + t * 16 + n16] = (bf16)gelu_t(acc[t][r] + bb);
    }
    // ---- step GEMM2 (K=128) -> new_e ----
#pragma unroll
    for (int t = 0; t < 8; ++t) acc[t] = z;
#pragma unroll
    for (int kc = 0; kc < 128; kc += 32) {
        bf16x8 a = *(const bf16x8*)&Hw[n16 * 136 + kc + quad * 8];
        const bf16* bp = Ws1 + ((size_t)(((kc >> 3) + quad) * 128 + n16)) * 8;
#pragma unroll
        for (int t = 0; t < 8; ++t) {
            bf16x8 b = *(const bf16x8*)(bp + t * 128);
            acc[t] = __builtin_amdgcn_mfma_f32_16x16x32_bf16(a, b, acc[t], 0, 0, 0);
        }
    }
    // store new_e (guarded)
#pragma unroll
    for (int t = 0; t < 8; ++t) {
        float bb = bs1[t * 16 + n16];
#pragma unroll
        for (int r = 0; r < 4; ++r) {
            int row = m0 + w * 16 + quad * 4 + r;
            if (row < E)
                newe[(size_t)row * 128 + t * 16 + n16] = (bf16)(acc[t][r] + bb);
        }
    }
}

// ---------------- node kernels ----------------
// MODE 0: embed nodes  (K1=32, raw 7)  fp32 in  -> bf16 nh_b
// MODE 3: node update  (K1=256) bf16 nh_b + bf16 recvb -> bf16 nh_b in-place, skip+LN
// MODE 5: node update + FUSED decode -> fp32 out[N,3]
template <int MODE, int K1, int RAWF>
__global__ __launch_bounds__(256, 4) void mlp2_kernel(
    const void* __restrict__ Araw0v, const bf16* __restrict__ Araw1b,
    const bf16* __restrict__ W0p, const float* __restrict__ b0,
    const bf16* __restrict__ W1p, const float* __restrict__ b1,
    const float* __restrict__ ln_s, const float* __restrict__ ln_b,
    const bf16* __restrict__ Wd0, const float* __restrict__ db0,
    const float* __restrict__ dW1, const float* __restrict__ db1,
    void* out0v, int Mtotal)
{
    __shared__ __align__(16) bf16 Hsep[4 * 16 * 136];

    const int tid = threadIdx.x, lane = tid & 63, w = tid >> 6;
    const int n16 = lane & 15, quad = lane >> 4;
    const int m0 = blockIdx.x * 64;

    const float* Araw0f = (const float*)Araw0v;
    const bf16*  Araw0b = (const bf16*)Araw0v;
    float* out0f = (float*)out0v;
    bf16*  out0b = (bf16*)out0v;

    int m = m0 + w * 16 + n16;
    if (m >= Mtotal) m = Mtotal - 1;

    const f32x4 z = {0.0f, 0.0f, 0.0f, 0.0f};
    f32x4 acc[8];
#pragma unroll
    for (int t = 0; t < 8; ++t) acc[t] = z;

    // ---- GEMM1 ----
#pragma unroll
    for (int c = 0; c < K1 / 32; ++c) {
        const int k0 = c * 32 + quad * 8;
        bf16x8 a;
        if constexpr (MODE == 3 || MODE == 5) {
            if (c < 4) a = *(const bf16x8*)(Araw0b + (size_t)m * 128 + k0);
            else       a = *(const bf16x8*)(Araw1b + (size_t)m * 128 + (k0 - 128));
        } else {  // MODE 0: RAWF raw features (<8), only quad 0 nonzero
#pragma unroll
            for (int j = 0; j < 8; ++j) a[j] = (bf16)0.0f;
            if (quad == 0) {
#pragma unroll
                for (int j = 0; j < RAWF; ++j)
                    a[j] = (bf16)Araw0f[(size_t)m * RAWF + j];
            }
        }
        const bf16* bp = W0p + ((size_t)((c * 4 + quad) * 128 + n16)) * 8;
#pragma unroll
        for (int t = 0; t < 8; ++t) {
            bf16x8 b = *(const bf16x8*)(bp + t * 128);
            acc[t] = __builtin_amdgcn_mfma_f32_16x16x32_bf16(a, b, acc[t], 0, 0, 0);
        }
    }

    float b0v[8];
#pragma unroll
    for (int t = 0; t < 8; ++t) b0v[t] = b0[t * 16 + n16];

    // hidden -> A-layout via wave-private LDS slab
    bf16* Hw = &Hsep[w * 16 * 136];
#pragma unroll
    for (int t = 0; t < 8; ++t)
#pragma unroll
        for (int r = 0; r < 4; ++r)
            Hw[(quad * 4 + r) * 136 + t * 16 + n16] = (bf16)gelu_t(acc[t][r] + b0v[t]);

    // ---- GEMM2 (K=128) ----
#pragma unroll
    for (int t = 0; t < 8; ++t) acc[t] = z;
#pragma unroll
    for (int kc = 0; kc < 128; kc += 32) {
        bf16x8 a = *(const bf16x8*)&Hw[n16 * 136 + kc + quad * 8];
        const bf16* bp = W1p + ((size_t)(((kc >> 3) + quad) * 128 + n16)) * 8;
#pragma unroll
        for (int t = 0; t < 8; ++t) {
            bf16x8 b = *(const bf16x8*)(bp + t * 128);
            acc[t] = __builtin_amdgcn_mfma_f32_16x16x32_bf16(a, b, acc[t], 0, 0, 0);
        }
    }

    if constexpr (MODE == 0) {  // embed nodes: plain bf16 store
#pragma unroll
        for (int t = 0; t < 8; ++t) {
            float b1v = b1[t * 16 + n16];
#pragma unroll
            for (int r = 0; r < 4; ++r) {
                int row = m0 + w * 16 + quad * 4 + r;
                if (row < Mtotal)
                    out0b[(size_t)row * 128 + t * 16 + n16] = (bf16)(acc[t][r] + b1v);
            }
        }
        return;
    }

    // ---- MODE 3/5 epilogue: skip + LayerNorm ----
    float b1v[8], scl[8], bia[8];
#pragma unroll
    for (int t = 0; t < 8; ++t) {
        int col = t * 16 + n16;
        b1v[t] = b1[col]; scl[t] = ln_s[col]; bia[t] = ln_b[col];
    }
    int rowg[4];
#pragma unroll
    for (int r = 0; r < 4; ++r) rowg[r] = m0 + w * 16 + quad * 4 + r;
    float x[8][4];
    float sm[4] = {0, 0, 0, 0}, sq[4] = {0, 0, 0, 0};
#pragma unroll
    for (int t = 0; t < 8; ++t) {
        int col = t * 16 + n16;
#pragma unroll
        for (int r = 0; r < 4; ++r) {
            bool ok = rowg[r] < Mtotal;
            float v = acc[t][r] + b1v[t];
            float old = ok ? (float)Araw0b[(size_t)rowg[r] * 128 + col] : 0.0f;
            float xx = old + v;
            x[t][r] = xx; sm[r] += xx; sq[r] += xx * xx;
        }
    }
#pragma unroll
    for (int mm = 1; mm < 16; mm <<= 1)
#pragma unroll
        for (int r = 0; r < 4; ++r) {
            sm[r] += __shfl_xor(sm[r], mm);
            sq[r] += __shfl_xor(sq[r], mm);
        }
    float mean[4], inv[4];
#pragma unroll
    for (int r = 0; r < 4; ++r) {
        mean[r] = sm[r] * (1.0f / 128.0f);
        float var = sq[r] * (1.0f / 128.0f) - mean[r] * mean[r];
        inv[r] = rsqrtf(var + 1e-6f);
    }

    if constexpr (MODE == 3) {
#pragma unroll
        for (int t = 0; t < 8; ++t)
#pragma unroll
            for (int r = 0; r < 4; ++r)
                if (rowg[r] < Mtotal)
                    out0b[(size_t)rowg[r] * 128 + t * 16 + n16] =
                        (bf16)((x[t][r] - mean[r]) * inv[r] * scl[t] + bia[t]);
        return;
    }

    // ---- MODE 5: fused decode. LN out -> Hw (A-layout), GEMM1(Wd0), dot dW1 ----
#pragma unroll
    for (int t = 0; t < 8; ++t)
#pragma unroll
        for (int r = 0; r < 4; ++r)
            Hw[(quad * 4 + r) * 136 + t * 16 + n16] =
                (bf16)((x[t][r] - mean[r]) * inv[r] * scl[t] + bia[t]);

#pragma unroll
    for (int t = 0; t < 8; ++t) acc[t] = z;
#pragma unroll
    for (int kc = 0; kc < 128; kc += 32) {
        bf16x8 a = *(const bf16x8*)&Hw[n16 * 136 + kc + quad * 8];
        const bf16* bp = Wd0 + ((size_t)(((kc >> 3) + quad) * 128 + n16)) * 8;
#pragma unroll
        for (int t = 0; t < 8; ++t) {
            bf16x8 b = *(const bf16x8*)(bp + t * 128);
            acc[t] = __builtin_amdgcn_mfma_f32_16x16x32_bf16(a, b, acc[t], 0, 0, 0);
        }
    }
    {
        float p[4][3];
#pragma unroll
        for (int r = 0; r < 4; ++r) { p[r][0] = 0; p[r][1] = 0; p[r][2] = 0; }
#pragma unroll
        for (int t = 0; t < 8; ++t) {
            int col = t * 16 + n16;
            float bb = db0[col];
            float w0 = dW1[col * 3 + 0], w1 = dW1[col * 3 + 1], w2 = dW1[col * 3 + 2];
#pragma unroll
            for (int r = 0; r < 4; ++r) {
                float h = gelu_t(acc[t][r] + bb);
                p[r][0] += h * w0; p[r][1] += h * w1; p[r][2] += h * w2;
            }
        }
#pragma unroll
        for (int mm = 1; mm < 16; mm <<= 1)
#pragma unroll
            for (int r = 0; r < 4; ++r) {
                p[r][0] += __shfl_xor(p[r][0], mm);
                p[r][1] += __shfl_xor(p[r][1], mm);
                p[r][2] += __shfl_xor(p[r][2], mm);
            }
        if (n16 < 3) {
            float bb = db1[n16];
#pragma unroll
            for (int r = 0; r < 4; ++r)
                if (rowg[r] < Mtotal)
                    out0f[(size_t)rowg[r] * 3 + n16] = p[r][n16] + bb;
        }
    }
}

extern "C" void kernel_launch(void* const* d_in, const int* in_sizes, int n_in,
                              void* d_out, int out_size, void* d_ws, size_t ws_size,
                              hipStream_t stream) {
    const float* nodes   = (const float*)d_in[0];
    const float* edges   = (const float*)d_in[1];
    const float* glob    = (const float*)d_in[2];
    const int*   senders = (const int*)d_in[3];
    const int*   recvrs  = (const int*)d_in[4];
    const float* ne_W0 = (const float*)d_in[5],  *ne_b0 = (const float*)d_in[6];
    const float* ne_W1 = (const float*)d_in[7],  *ne_b1 = (const float*)d_in[8];
    const float* ee_W0 = (const float*)d_in[9],  *ee_b0 = (const float*)d_in[10];
    const float* ee_W1 = (const float*)d_in[11], *ee_b1 = (const float*)d_in[12];
    const float* eu_W0 = (const float*)d_in[13], *eu_b0 = (const float*)d_in[14];
    const float* eu_W1 = (const float*)d_in[15], *eu_b1 = (const float*)d_in[16];
    const float* nu_W0 = (const float*)d_in[17], *nu_b0 = (const float*)d_in[18];
    const float* nu_W1 = (const float*)d_in[19], *nu_b1 = (const float*)d_in[20];
    const float* ln_s  = (const float*)d_in[21], *ln_b  = (const float*)d_in[22];
    const float* dc_W0 = (const float*)d_in[23], *dc_b0 = (const float*)d_in[24];
    const float* dc_W1 = (const float*)d_in[25], *dc_b1 = (const float*)d_in[26];

    const int N = 50000, E = 500000;

    const int KD[13] = {32, 128, 32, 128, 384, 384, 128, 128, 256, 256, 128, 128, 128};
    const int KC[13] = {7, 128, 3, 128, 384, 384, 128, 128, 256, 256, 128, 128, 128};
    int pre[14]; pre[0] = 0;
    for (int i = 0; i < 13; ++i) pre[i + 1] = pre[i] + KD[i] * 128;
    const int totalPack = pre[13];

    char* ws = (char*)d_ws;
    size_t off = 0;
    auto alloc = [&](size_t bytes) -> char* {
        char* p = ws + off;
        off = (off + bytes + 255) & ~(size_t)255;
        return p;
    };
    bf16*  Wp      = (bf16*)alloc((size_t)totalPack * 2);
    float* b0e_eu  = (float*)alloc(2 * 128 * 4);
    float* b0e_nu  = (float*)alloc(2 * 128 * 4);
    bf16*  nh_b    = (bf16*)alloc((size_t)N * 128 * 2);      // 12.8 MB
    bf16*  recvb   = (bf16*)alloc((size_t)N * 128 * 2);      // 12.8 MB
    bf16*  newe    = (bf16*)alloc((size_t)E * 128 * 2);      // 128 MB
    int*   deg     = (int*)alloc((size_t)N * 4);
    int*   cursor  = (int*)alloc((size_t)N * 4);
    int*   bsum    = (int*)alloc(256 * 4);
    float* edges_s = (float*)alloc((size_t)E * 3 * 4);       // 6 MB sorted raw feats
    int*   sendp   = (int*)alloc((size_t)E * 4);
    int*   recvp   = (int*)alloc((size_t)E * 4);
    // base ~164 MB (proven-good envelope)

    if (off > ws_size) return;  // base must fit; clean diagnostic otherwise

    // ws-adaptive: materialize eh0 only if the workspace is big enough
    bf16* eh0g = nullptr;
    if (off + (size_t)E * 128 * 2 + 256 <= ws_size)
        eh0g = (bf16*)alloc((size_t)E * 128 * 2);            // +128 MB

    PackArgs pa;
    const float* srcs[13] = {
        ne_W0, ne_W1, ee_W0, ee_W1,
        eu_W0, eu_W0 + (size_t)386 * 128,
        eu_W1, eu_W1 + (size_t)128 * 128,
        nu_W0, nu_W0 + (size_t)258 * 128,
        nu_W1, nu_W1 + (size_t)128 * 128,
        dc_W0};
    for (int i = 0; i < 13; ++i) { pa.d[i].src = srcs[i]; pa.d[i].Kcopy = KC[i]; pa.d[i].dstOff = pre[i]; }

    pack_all_kernel<<<(totalPack + 255) / 256, 256, 0, stream>>>(pa, Wp, totalPack);
    fold_bias_kernel<<<1, 128, 0, stream>>>(glob, eu_W0, eu_b0, nu_W0, nu_b0, b0e_eu, b0e_nu);

    // ---- receiver counting-sort ----
    const int gEdge = (E + 255) / 256;
    const int nb = (N + 255) / 256;
    zero_kernel<<<(N / 4 + 255) / 256, 256, 0, stream>>>((float4*)deg, N / 4);
    hist_kernel<<<gEdge, 256, 0, stream>>>(recvrs, deg, E);
    scan_part_kernel<<<nb, 256, 0, stream>>>(deg, cursor, bsum, N);
    scan_top_kernel<<<1, 256, 0, stream>>>(bsum, nb);
    scan_add_kernel<<<nb, 256, 0, stream>>>(cursor, bsum, N);
    scatter_kernel<<<gEdge, 256, 0, stream>>>(senders, recvrs, edges, cursor,
                                              edges_s, sendp, recvp, E);
    // cursor now holds CSR end-offsets

    const int gN = (N + 63) / 64, gE = (E + 63) / 64;
    mlp2_kernel<0, 32, 7><<<gN, 256, 0, stream>>>(
        nodes, nullptr, Wp + pre[0], ne_b0, Wp + pre[1], ne_b1,
        nullptr, nullptr, nullptr, nullptr, nullptr, nullptr, nh_b, N);

    for (int s = 0; s < 2; ++s) {
        if (s == 0) {
            if (eh0g)
                edge_kernel<0, 1><<<gE, 256, 0, stream>>>(
                    edges_s, sendp, recvp, nh_b, newe, eh0g,
                    Wp + pre[2], ee_b0, Wp + pre[3], ee_b1, ln_s, ln_b,
                    Wp + pre[4], b0e_eu, Wp + pre[6], eu_b1, E);
            else
                edge_kernel<0, 0><<<gE, 256, 0, stream>>>(
                    edges_s, sendp, recvp, nh_b, newe, nullptr,
                    Wp + pre[2], ee_b0, Wp + pre[3], ee_b1, ln_s, ln_b,
                    Wp + pre[4], b0e_eu, Wp + pre[6], eu_b1, E);
        } else {
            if (eh0g)
                edge_kernel<1, 1><<<gE, 256, 0, stream>>>(
                    edges_s, sendp, recvp, nh_b, newe, eh0g,
                    Wp + pre[2], ee_b0, Wp + pre[3], ee_b1, ln_s, ln_b,
                    Wp + pre[5], b0e_eu + 128, Wp + pre[7], eu_b1 + 128, E);
            else
                edge_kernel<1, 0><<<gE, 256, 0, stream>>>(
                    edges_s, sendp, recvp, nh_b, newe, nullptr,
                    Wp + pre[2], ee_b0, Wp + pre[3], ee_b1, ln_s, ln_b,
                    Wp + pre[5], b0e_eu + 128, Wp + pre[7], eu_b1 + 128, E);
        }
        segsum_kernel<<<(N + 3) / 4, 256, 0, stream>>>(newe, cursor, recvb, N);
        if (s == 0)
            mlp2_kernel<3, 256, 0><<<gN, 256, 0, stream>>>(
                nh_b, recvb, Wp + pre[8], b0e_nu,
                Wp + pre[10], nu_b1, ln_s, ln_b,
                nullptr, nullptr, nullptr, nullptr, nh_b, N);
        else
            mlp2_kernel<5, 256, 0><<<gN, 256, 0, stream>>>(
                nh_b, recvb, Wp + pre[9], b0e_nu + 128,
                Wp + pre[11], nu_b1 + 128, ln_s, ln_b,
                Wp + pre[12], dc_b0, dc_W1, dc_b1, d_out, N);
    }
}